// Round 4
// baseline (1780.885 us; speedup 1.0000x reference)
//
#include <hip/hip_runtime.h>
#include <stdint.h>

#define N_CL 40000
#define NF   20
#define DD   128
#define SS   512
#define NW   625                 // N_CL / 64
#define PARTN (NW * SS)
#define NEGF (-3.0e38f)
#define DISCOUNT 0.995f
#define ECOEF 0.1f

typedef __attribute__((ext_vector_type(2))) float float2v;

__device__ __forceinline__ float rl(float v, int k) {
    return __int_as_float(__builtin_amdgcn_readlane(__float_as_int(v), k));
}
__device__ __forceinline__ float rcpf(float x) { return __builtin_amdgcn_rcpf(x); }
__device__ __forceinline__ float sigm(float x) { return rcpf(1.f + __expf(-x)); }
__device__ __forceinline__ float tanh_fast(float x) { return 1.f - 2.f * rcpf(1.f + __expf(2.f * x)); }

// ---------------- pack masks: ballot 64 int32 flags -> one u64 word -------------
__global__ __launch_bounds__(256) void k_pack(const int* __restrict__ sel,
                                              const int* __restrict__ good,
                                              unsigned long long* __restrict__ selw,
                                              unsigned long long* __restrict__ goodw) {
    int wave = (blockIdx.x * 256 + threadIdx.x) >> 6;   // 0..2499
    int lane = threadIdx.x & 63;
    for (int i = 0; i < 128; ++i) {
        int chunk = wave * 128 + i;                     // 0..319999
        int s = chunk / NW;
        int b = chunk - s * NW;
        int idx = s * N_CL + b * 64 + lane;
        unsigned long long bs = __ballot(sel[idx]  != 0);
        unsigned long long bg = __ballot(good[idx] != 0);
        if (lane == 0) { selw[s * NW + b] = bs; goodw[s * NW + b] = bg; }
    }
}

// ---------------- hidden = relu(features @ W1 + b1) ----------------------------
__global__ __launch_bounds__(256) void k_hidden(const float* __restrict__ feat,
                                                const float* __restrict__ W1,
                                                const float* __restrict__ b1,
                                                float* __restrict__ hidden) {
    int t = threadIdx.x;
    int j = t & 127;
    int r = blockIdx.x * 2 + (t >> 7);
    const float* fr = feat + r * NF;
    float acc = b1[j];
#pragma unroll
    for (int f = 0; f < NF; ++f) acc += fr[f] * W1[f * DD + j];
    hidden[r * DD + j] = fmaxf(acc, 0.f);
}

// ---------------- W2T[d][j] = W2[j][d] -----------------------------------------
__global__ __launch_bounds__(256) void k_w2t(const float* __restrict__ W2,
                                             float* __restrict__ W2T) {
    int i = blockIdx.x * 256 + threadIdx.x;   // 0..16383
    int r = i >> 7, c = i & 127;
    W2T[c * DD + r] = W2[i];
}

// ---------------- emb = hidden @ W2 + b2 ---------------------------------------
__global__ __launch_bounds__(256, 2) void k_emb(const float* __restrict__ hidden,
                                                const float* __restrict__ W2T,
                                                const float* __restrict__ b2,
                                                float* __restrict__ emb) {
    int t = threadIdx.x;
    int d = t & 127;
    int rh = t >> 7;                 // 0/1 : wave-uniform
    const float4* w2r = (const float4*)(W2T + d * DD);
    float4 w[32];
#pragma unroll
    for (int q = 0; q < 32; ++q) w[q] = w2r[q];
    float bb = b2[d];
    int rbase = blockIdx.x * 64 + rh * 32;
    for (int rr = 0; rr < 32; ++rr) {
        int r = rbase + rr;
        const float4* hr = (const float4*)(hidden + r * DD);   // wave-uniform
        float acc = bb;
#pragma unroll
        for (int q = 0; q < 32; ++q) {
            float4 h4 = hr[q];
            acc += h4.x * w[q].x + h4.y * w[q].y + h4.z * w[q].z + h4.w * w[q].w;
        }
        emb[r * DD + d] = acc;
    }
}

// ---- P2[s][pos][g] = bih[j]+bhh[j] + Wih[j].emb[sel_idx[s]],  j=g*128+pos ----
__global__ __launch_bounds__(256) void k_pgemm(const float* __restrict__ emb,
                                               const int* __restrict__ sel_idx,
                                               const float* __restrict__ Wih,
                                               const float* __restrict__ bih,
                                               const float* __restrict__ bhh,
                                               float* __restrict__ P2) {
    __shared__ __align__(16) float x8[8][DD];
    int t = threadIdx.x;
    int sb = blockIdx.x * 8;
    for (int i = t; i < 8 * DD; i += 256) {
        int sl = i >> 7, k = i & 127;
        x8[sl][k] = emb[sel_idx[sb + sl] * DD + k];
    }
    __syncthreads();
    for (int jj = t; jj < 512; jj += 256) {
        float base = bih[jj] + bhh[jj];
        float acc[8];
#pragma unroll
        for (int s8 = 0; s8 < 8; ++s8) acc[s8] = base;
        const float4* wr = (const float4*)(Wih + jj * DD);
        for (int q = 0; q < 32; ++q) {
            float4 w4 = wr[q];
#pragma unroll
            for (int s8 = 0; s8 < 8; ++s8) {
                const float4* xs = (const float4*)&x8[s8][0];
                float4 xv = xs[q];
                acc[s8] += w4.x * xv.x + w4.y * xv.y + w4.z * xv.z + w4.w * xv.w;
            }
        }
        int pos = jj & 127, g = jj >> 7;
        for (int s8 = 0; s8 < 8; ++s8) P2[(sb + s8) * 512 + pos * 4 + g] = acc[s8];
    }
}

// ---------------- sequential LSTM scan: M-split, 1 gate/thread, fp32 exact -----
// 512 threads = 8 waves. Thread t owns gate t: 128 weights = 64 float2 K-pairs
// (contiguous, 128 VGPRs -> stays under the 256 arch-VGPR cap; no demotion).
__global__ __launch_bounds__(512, 1) void k_lstm(const float* __restrict__ Whh,
                                                 const float* __restrict__ P2,
                                                 const float* __restrict__ init_h,
                                                 const float* __restrict__ init_c,
                                                 float* __restrict__ H) {
    __shared__ __align__(16) float pbuf[2][8 * 512];   // 32 KB: two 8-step P chunks
    __shared__ __align__(16) float gates_sh[512];      // [pos*4 + gtype]
    __shared__ float h_sh[DD];
    int t = threadIdx.x, w = t >> 6, l = t & 63;

    // wp[k2] = {Whh[t*128 + 2*k2], Whh[t*128 + 2*k2 + 1]}  (K-pairs, contiguous)
    float2v wp[64];
    {
        const float4* wr = (const float4*)(Whh + t * DD);
#pragma unroll
        for (int q = 0; q < 32; ++q) {
            float4 v = wr[q];
            wp[2 * q]     = float2v{v.x, v.y};
            wp[2 * q + 1] = float2v{v.z, v.w};
        }
    }

    // async stage of one 8-step P chunk (16 KB) into pbuf[bufi]
    auto issue = [&](int cidx, int bufi) {
        if (cidx >= SS / 8) return;
        const float* src = P2 + cidx * 4096 + w * 512 + l * 4;
        float* dst = &pbuf[bufi][w * 512];
#pragma unroll
        for (int i = 0; i < 2; ++i) {
            __builtin_amdgcn_global_load_lds(
                (const __attribute__((address_space(1))) void*)(src + i * 256),
                (__attribute__((address_space(3))) void*)(dst + i * 256),
                16, 0, 0);
        }
    };

    float c = 0.f;
    if (t < DD) { h_sh[t] = init_h[t]; c = init_c[t]; H[t] = init_h[t]; }
    issue(0, 0);
    __syncthreads();   // drains chunk 0, publishes h_sh

    float hbuf[8];
    int pos = t & 127, gt = t >> 7;
    for (int s = 0; s < SS; ++s) {
        int buf = (s >> 3) & 1;
        if ((s & 7) == 0) issue((s >> 3) + 1, buf ^ 1);
        float vh0 = h_sh[l], vh1 = h_sh[64 + l];   // lane j holds h[j] / h[64+j]
        float2v a0{0.f, 0.f}, a1{0.f, 0.f}, a2{0.f, 0.f}, a3{0.f, 0.f};
#pragma unroll
        for (int k2 = 0; k2 < 32; k2 += 4) {
            a0 += wp[k2]     * float2v{rl(vh0, 2 * k2),     rl(vh0, 2 * k2 + 1)};
            a1 += wp[k2 + 1] * float2v{rl(vh0, 2 * k2 + 2), rl(vh0, 2 * k2 + 3)};
            a2 += wp[k2 + 2] * float2v{rl(vh0, 2 * k2 + 4), rl(vh0, 2 * k2 + 5)};
            a3 += wp[k2 + 3] * float2v{rl(vh0, 2 * k2 + 6), rl(vh0, 2 * k2 + 7)};
        }
#pragma unroll
        for (int k2 = 0; k2 < 32; k2 += 4) {
            a0 += wp[32 + k2]     * float2v{rl(vh1, 2 * k2),     rl(vh1, 2 * k2 + 1)};
            a1 += wp[32 + k2 + 1] * float2v{rl(vh1, 2 * k2 + 2), rl(vh1, 2 * k2 + 3)};
            a2 += wp[32 + k2 + 2] * float2v{rl(vh1, 2 * k2 + 4), rl(vh1, 2 * k2 + 5)};
            a3 += wp[32 + k2 + 3] * float2v{rl(vh1, 2 * k2 + 6), rl(vh1, 2 * k2 + 7)};
        }
        float2v asum = (a0 + a1) + (a2 + a3);
        gates_sh[pos * 4 + gt] = asum.x + asum.y;
        __syncthreads();
        if (t < DD) {
            float4 pv = *(const float4*)&pbuf[buf][(s & 7) * 512 + t * 4];
            float4 gv = *(const float4*)&gates_sh[t * 4];
            float gi = gv.x + pv.x;
            float gf = gv.y + pv.y;
            float gg = gv.z + pv.z;
            float go = gv.w + pv.w;
            float ii = sigm(gi), ff = sigm(gf), tg = tanh_fast(gg), oo = sigm(go);
            c = ff * c + ii * tg;
            float hn = oo * tanh_fast(c);
            h_sh[t] = hn;
            if (s < SS - 1) {
                hbuf[s & 7] = hn;
                if ((s & 7) == 7) {            // batched H store: one drain per 8 steps
#pragma unroll
                    for (int k2 = 0; k2 < 8; ++k2) H[(s - 6 + k2) * DD + t] = hbuf[k2];
                }
            }
        }
        __syncthreads();
    }
    if (t < DD) {   // tail: steps 504..510 -> H[505..511]
#pragma unroll
        for (int k2 = 0; k2 < 7; ++k2) H[(505 + k2) * DD + t] = hbuf[k2];
    }
}

// ------- phase C: pair-split online softmax. 2 threads/step, 64 h-regs each ----
// grid 1250: blockIdx>>1 = row-block, blockIdx&1 = step-half. Thread pair
// (2p, 2p+1) handles step sh*256+p; lane e holds h[e*64 .. e*64+64).
__global__ __launch_bounds__(512, 1) void k_logits(const float* __restrict__ emb,
                                                   const float* __restrict__ H,
                                                   const unsigned long long* __restrict__ selw,
                                                   const unsigned long long* __restrict__ goodw,
                                                   float* __restrict__ part) {
    int b = blockIdx.x >> 1;
    int sh = blockIdx.x & 1;
    int t = threadIdx.x;
    int p = t >> 1, e = t & 1;
    int s = sh * 256 + p;
    float4 h4[16];                                   // 64 VGPRs
    const float4* hr = (const float4*)(H + s * DD + e * 64);
#pragma unroll
    for (int q = 0; q < 16; ++q) h4[q] = hr[q];
    unsigned long long sw = selw[s * NW + b];
    unsigned long long gw = goodw[s * NW + b];
    float m = NEGF, se = 0.f, sl = 0.f, slg = 0.f;
    int rowbase = b * 64;
    for (int r = 0; r < 64; ++r) {
        const float4* er = (const float4*)(emb + (rowbase + r) * DD + e * 64);
        float a0 = 0.f, a1 = 0.f, a2 = 0.f, a3 = 0.f;
#pragma unroll
        for (int q = 0; q < 16; q += 4) {
            float4 e0 = er[q], e1 = er[q + 1], e2 = er[q + 2], e3 = er[q + 3];
            a0 += e0.x * h4[q].x + e0.y * h4[q].y + e0.z * h4[q].z + e0.w * h4[q].w;
            a1 += e1.x * h4[q + 1].x + e1.y * h4[q + 1].y + e1.z * h4[q + 1].z + e1.w * h4[q + 1].w;
            a2 += e2.x * h4[q + 2].x + e2.y * h4[q + 2].y + e2.z * h4[q + 2].z + e2.w * h4[q + 2].w;
            a3 += e3.x * h4[q + 3].x + e3.y * h4[q + 3].y + e3.z * h4[q + 3].z + e3.w * h4[q + 3].w;
        }
        float half = (a0 + a1) + (a2 + a3);
        float acc = half + __shfl_xor(half, 1);      // combine the two D-halves
        float selb  = (float)((sw >> r) & 1ull);
        float goodb = (float)((gw >> r) & 1ull);
        float lm = (selb > 0.f) ? acc : NEGF;
        float nm = fmaxf(m, lm);
        float a = __expf(m - nm);
        float bx = selb * __expf(lm - nm);
        se = se * a + bx;
        sl = sl * a + bx * acc;
        m = nm;
        slg += goodb * acc;
    }
    if (e == 0) {
        int o = b * SS + s;
        part[0 * PARTN + o] = m;
        part[1 * PARTN + o] = se;
        part[2 * PARTN + o] = sl;
        part[3 * PARTN + o] = slg;
        part[4 * PARTN + o] = (float)__popcll(sw);
        part[5 * PARTN + o] = (float)__popcll(gw);
    }
}

// ---------------- per-step merge of 625 block partials -------------------------
__global__ __launch_bounds__(64) void k_reduce(const float* __restrict__ part,
                                               float* __restrict__ Aout,
                                               float* __restrict__ Bout,
                                               float* __restrict__ actout) {
    int s = blockIdx.x;
    int t = threadIdx.x;     // 64 threads, one wave
    float m = NEGF, se = 0.f, sl = 0.f, slg = 0.f, np = 0.f, ng = 0.f;
    for (int b = t; b < NW; b += 64) {
        int o = b * SS + s;
        float m2  = part[0 * PARTN + o];
        float se2 = part[1 * PARTN + o];
        float sl2 = part[2 * PARTN + o];
        slg += part[3 * PARTN + o];
        np  += part[4 * PARTN + o];
        ng  += part[5 * PARTN + o];
        float nm = fmaxf(m, m2);
        float a = __expf(m - nm), a2 = __expf(m2 - nm);
        se = se * a + se2 * a2;
        sl = sl * a + sl2 * a2;
        m = nm;
    }
    for (int off = 32; off > 0; off >>= 1) {
        float m2  = __shfl_xor(m, off);
        float se2 = __shfl_xor(se, off);
        float sl2 = __shfl_xor(sl, off);
        slg += __shfl_xor(slg, off);
        np  += __shfl_xor(np, off);
        ng  += __shfl_xor(ng, off);
        float nm = fmaxf(m, m2);
        float a = __expf(m - nm), a2 = __expf(m2 - nm);
        se = se * a + se2 * a2;
        sl = sl * a + sl2 * a2;
        m = nm;
    }
    if (t == 0) {
        float lse = m + logf(se);
        float nbad = np - ng;
        int active = (ng > 0.5f) && (nbad > 0.5f);
        float ce = (ng * lse - slg) / fmaxf(ng, 1.f);
        float A = (nbad / fmaxf(np, 1.f)) * ce;
        float minus_ent = sl / se - lse;
        float B = ECOEF * (minus_ent / logf(fmaxf(np, 2.0f)));
        Aout[s] = A; Bout[s] = B; actout[s] = active ? 1.f : 0.f;
    }
}

// ---------------- exact sequential discount prefix + final sum -----------------
__global__ __launch_bounds__(64) void k_final(const float* __restrict__ A,
                                              const float* __restrict__ B,
                                              const float* __restrict__ act,
                                              float* __restrict__ out) {
    int lane = threadIdx.x;
    float loss = 0.f;
    int base = 0;
    for (int ch = 0; ch < 8; ++ch) {
        int s = ch * 64 + lane;
        bool a = act[s] > 0.5f;
        unsigned long long bal = __ballot(a);
        unsigned long long ltmask = (lane == 0) ? 0ull : (~0ull >> (64 - lane));
        int pre = __popcll(bal & ltmask);
        if (a) {
            float f = powf(DISCOUNT, (float)(base + pre));
            loss += f * A[s] + B[s];
        }
        base += __popcll(bal);
    }
    for (int off = 32; off > 0; off >>= 1) loss += __shfl_xor(loss, off);
    if (lane == 0) out[0] = loss / fmaxf((float)base, 1.f);
}

extern "C" void kernel_launch(void* const* d_in, const int* in_sizes, int n_in,
                              void* d_out, int out_size, void* d_ws, size_t ws_size,
                              hipStream_t stream) {
    (void)in_sizes; (void)n_in; (void)out_size; (void)ws_size;
    const float* feat    = (const float*)d_in[0];
    const int*   sel     = (const int*)d_in[1];
    const int*   good    = (const int*)d_in[2];
    const int*   sel_idx = (const int*)d_in[3];
    const float* W1      = (const float*)d_in[4];
    const float* b1      = (const float*)d_in[5];
    const float* W2      = (const float*)d_in[6];
    const float* b2      = (const float*)d_in[7];
    const float* init_h  = (const float*)d_in[8];
    const float* init_c  = (const float*)d_in[9];
    const float* Wih     = (const float*)d_in[10];
    const float* Whh     = (const float*)d_in[11];
    const float* bih     = (const float*)d_in[12];
    const float* bhh     = (const float*)d_in[13];
    float* out = (float*)d_out;
    char* ws = (char*)d_ws;

    float* emb    = (float*)(ws + 0);                         // 20,480,000 B
    float* hidden = (float*)(ws + 20480000);                  // 20,480,000 B
    float* W2T    = (float*)(ws + 40960000);                  // 65,536 B
    float* P2     = (float*)(ws + 41025536);                  // 1,048,576 B
    float* H      = (float*)(ws + 42074112);                  // 262,144 B
    unsigned long long* selw  = (unsigned long long*)(ws + 42336256);   // 2,560,000 B
    unsigned long long* goodw = (unsigned long long*)(ws + 44896256);   // 2,560,000 B
    float* part   = (float*)(ws + 47456256);                  // 7,680,000 B
    float* Aarr   = (float*)(ws + 55136256);                  // 2048 B
    float* Barr   = (float*)(ws + 55138304);                  // 2048 B
    float* actarr = (float*)(ws + 55140352);                  // 2048 B

    k_pack  <<<NW, 256, 0, stream>>>(sel, good, selw, goodw);
    k_hidden<<<N_CL / 2, 256, 0, stream>>>(feat, W1, b1, hidden);
    k_w2t   <<<64, 256, 0, stream>>>(W2, W2T);
    k_emb   <<<NW, 256, 0, stream>>>(hidden, W2T, b2, emb);
    k_pgemm <<<64, 256, 0, stream>>>(emb, sel_idx, Wih, bih, bhh, P2);
    k_lstm  <<<1, 512, 0, stream>>>(Whh, P2, init_h, init_c, H);
    k_logits<<<NW * 2, 512, 0, stream>>>(emb, H, selw, goodw, part);
    k_reduce<<<SS, 64, 0, stream>>>(part, Aarr, Barr, actarr);
    k_final <<<1, 64, 0, stream>>>(Aarr, Barr, actarr, out);
}

// Round 5
// 1070.311 us; speedup vs baseline: 1.6639x; 1.6639x over previous
//
#include <hip/hip_runtime.h>
#include <stdint.h>

#define N_CL 40000
#define NF   20
#define DD   128
#define SS   512
#define NW   625                 // N_CL / 64
#define PARTN (NW * SS)
#define NEGF (-3.0e38f)
#define DISCOUNT 0.995f
#define ECOEF 0.1f

typedef __attribute__((ext_vector_type(4))) float f32x4;

__device__ __forceinline__ float rl(float v, int k) {
    return __int_as_float(__builtin_amdgcn_readlane(__float_as_int(v), k));
}
__device__ __forceinline__ float rcpf(float x) { return __builtin_amdgcn_rcpf(x); }
__device__ __forceinline__ float sigm(float x) { return rcpf(1.f + __expf(-x)); }
__device__ __forceinline__ float tanh_fast(float x) { return 1.f - 2.f * rcpf(1.f + __expf(2.f * x)); }

// ---------------- pack masks: ballot 64 int32 flags -> one u64 word -------------
__global__ __launch_bounds__(256) void k_pack(const int* __restrict__ sel,
                                              const int* __restrict__ good,
                                              unsigned long long* __restrict__ selw,
                                              unsigned long long* __restrict__ goodw) {
    int wave = (blockIdx.x * 256 + threadIdx.x) >> 6;   // 0..2499
    int lane = threadIdx.x & 63;
    for (int i = 0; i < 128; ++i) {
        int chunk = wave * 128 + i;                     // 0..319999
        int s = chunk / NW;
        int b = chunk - s * NW;
        int idx = s * N_CL + b * 64 + lane;
        unsigned long long bs = __ballot(sel[idx]  != 0);
        unsigned long long bg = __ballot(good[idx] != 0);
        if (lane == 0) { selw[s * NW + b] = bs; goodw[s * NW + b] = bg; }
    }
}

// ---------------- hidden = relu(features @ W1 + b1) ----------------------------
__global__ __launch_bounds__(256) void k_hidden(const float* __restrict__ feat,
                                                const float* __restrict__ W1,
                                                const float* __restrict__ b1,
                                                float* __restrict__ hidden) {
    int t = threadIdx.x;
    int j = t & 127;
    int r = blockIdx.x * 2 + (t >> 7);
    const float* fr = feat + r * NF;
    float acc = b1[j];
#pragma unroll
    for (int f = 0; f < NF; ++f) acc += fr[f] * W1[f * DD + j];
    hidden[r * DD + j] = fmaxf(acc, 0.f);
}

// ---------------- emb = hidden @ W2 + b2  (LDS-tiled register GEMM) ------------
// 625 blocks x 256 threads. Tile: 64 rows x 128 cols. Thread (c4 = t&31,
// rg = t>>5) computes 8 rows x 4 cols, all accumulators NAMED (no demotion).
#define EMB_FMA(RR) { f32x4 hvv = *(const f32x4*)&hs[rg * 8 + RR][q]; \
    acc##RR += wv0 * hvv.x + wv1 * hvv.y + wv2 * hvv.z + wv3 * hvv.w; }
#define EMB_ST(RR) *(f32x4*)&emb[(rbase + rg * 8 + RR) * DD + c4 * 4] = acc##RR + bv;

__global__ __launch_bounds__(256) void k_emb(const float* __restrict__ hidden,
                                             const float* __restrict__ W2,
                                             const float* __restrict__ b2,
                                             float* __restrict__ emb) {
    __shared__ float hs[64][132];                     // +4 pad, 33.8 KB
    int t = threadIdx.x;
    int rbase = blockIdx.x * 64;
#pragma unroll
    for (int i = t; i < 2048; i += 256) {             // stage 64x128 hidden tile
        int r = i >> 5, k4 = i & 31;
        *(f32x4*)&hs[r][k4 * 4] = *(const f32x4*)&hidden[(rbase + r) * DD + k4 * 4];
    }
    __syncthreads();
    int c4 = t & 31, rg = t >> 5;
    f32x4 acc0{0,0,0,0}, acc1{0,0,0,0}, acc2{0,0,0,0}, acc3{0,0,0,0},
          acc4{0,0,0,0}, acc5{0,0,0,0}, acc6{0,0,0,0}, acc7{0,0,0,0};
    for (int q = 0; q < DD; q += 4) {
        f32x4 wv0 = *(const f32x4*)&W2[(q + 0) * DD + c4 * 4];
        f32x4 wv1 = *(const f32x4*)&W2[(q + 1) * DD + c4 * 4];
        f32x4 wv2 = *(const f32x4*)&W2[(q + 2) * DD + c4 * 4];
        f32x4 wv3 = *(const f32x4*)&W2[(q + 3) * DD + c4 * 4];
        EMB_FMA(0) EMB_FMA(1) EMB_FMA(2) EMB_FMA(3)
        EMB_FMA(4) EMB_FMA(5) EMB_FMA(6) EMB_FMA(7)
    }
    f32x4 bv = *(const f32x4*)&b2[c4 * 4];
    EMB_ST(0) EMB_ST(1) EMB_ST(2) EMB_ST(3)
    EMB_ST(4) EMB_ST(5) EMB_ST(6) EMB_ST(7)
}

// ---- P2[s][pos][g] = bih[j]+bhh[j] + Wih[j].emb[sel_idx[s]],  j=g*128+pos ----
__global__ __launch_bounds__(256) void k_pgemm(const float* __restrict__ emb,
                                               const int* __restrict__ sel_idx,
                                               const float* __restrict__ Wih,
                                               const float* __restrict__ bih,
                                               const float* __restrict__ bhh,
                                               float* __restrict__ P2) {
    __shared__ __align__(16) float x8[8][DD];
    int t = threadIdx.x;
    int sb = blockIdx.x * 8;
    for (int i = t; i < 8 * DD; i += 256) {
        int sl = i >> 7, k = i & 127;
        x8[sl][k] = emb[sel_idx[sb + sl] * DD + k];
    }
    __syncthreads();
    for (int jj = t; jj < 512; jj += 256) {
        float base = bih[jj] + bhh[jj];
        float acc[8];
#pragma unroll
        for (int s8 = 0; s8 < 8; ++s8) acc[s8] = base;
        const float4* wr = (const float4*)(Wih + jj * DD);
        for (int q = 0; q < 32; ++q) {
            float4 w4 = wr[q];
#pragma unroll
            for (int s8 = 0; s8 < 8; ++s8) {
                const float4* xs = (const float4*)&x8[s8][0];
                float4 xv = xs[q];
                acc[s8] += w4.x * xv.x + w4.y * xv.y + w4.z * xv.z + w4.w * xv.w;
            }
        }
        int pos = jj & 127, g = jj >> 7;
        for (int s8 = 0; s8 < 8; ++s8) P2[(sb + s8) * 512 + pos * 4 + g] = acc[s8];
    }
}

// ---------------- sequential LSTM scan: 1 gate/thread, NAMED weight regs -------
// 512 threads = 8 waves. Thread t owns Whh row t: 32 named float4 = 128 VGPRs.
// Scalar fmaf lets readlane results fold as the single SGPR operand of v_fma.
#define MV4(W, HV, L) \
    a0 = fmaf(W.x, rl(HV, (L) + 0), a0); \
    a1 = fmaf(W.y, rl(HV, (L) + 1), a1); \
    a2 = fmaf(W.z, rl(HV, (L) + 2), a2); \
    a3 = fmaf(W.w, rl(HV, (L) + 3), a3);

__global__ __launch_bounds__(512, 1) void k_lstm(const float* __restrict__ Whh,
                                                 const float* __restrict__ P2,
                                                 const float* __restrict__ init_h,
                                                 const float* __restrict__ init_c,
                                                 float* __restrict__ H) {
    __shared__ __align__(16) float pbuf[2][8 * 512];   // 32 KB: two 8-step P chunks
    __shared__ __align__(16) float gates_sh[512];      // [pos*4 + gtype]
    __shared__ float h_sh[DD];
    int t = threadIdx.x, w = t >> 6, l = t & 63;

    const float4* wr = (const float4*)(Whh + t * DD);
    float4 w0 = wr[0],  w1 = wr[1],  w2 = wr[2],  w3 = wr[3],
           w4 = wr[4],  w5 = wr[5],  w6 = wr[6],  w7 = wr[7],
           w8 = wr[8],  w9 = wr[9],  w10 = wr[10], w11 = wr[11],
           w12 = wr[12], w13 = wr[13], w14 = wr[14], w15 = wr[15],
           w16 = wr[16], w17 = wr[17], w18 = wr[18], w19 = wr[19],
           w20 = wr[20], w21 = wr[21], w22 = wr[22], w23 = wr[23],
           w24 = wr[24], w25 = wr[25], w26 = wr[26], w27 = wr[27],
           w28 = wr[28], w29 = wr[29], w30 = wr[30], w31 = wr[31];

    auto issue = [&](int cidx, int bufi) {             // stage 8-step P chunk
        if (cidx >= SS / 8) return;
        const float* src = P2 + cidx * 4096 + w * 512 + l * 4;
        float* dst = &pbuf[bufi][w * 512];
#pragma unroll
        for (int i = 0; i < 2; ++i) {
            __builtin_amdgcn_global_load_lds(
                (const __attribute__((address_space(1))) void*)(src + i * 256),
                (__attribute__((address_space(3))) void*)(dst + i * 256),
                16, 0, 0);
        }
    };

    float c = 0.f;
    if (t < DD) { h_sh[t] = init_h[t]; c = init_c[t]; H[t] = init_h[t]; }
    issue(0, 0);
    __syncthreads();

    float hbuf[8];
    int pos = t & 127;
    for (int s = 0; s < SS; ++s) {
        int buf = (s >> 3) & 1;
        if ((s & 7) == 0) issue((s >> 3) + 1, buf ^ 1);
        float vh0 = h_sh[l], vh1 = h_sh[64 + l];
        float a0 = 0.f, a1 = 0.f, a2 = 0.f, a3 = 0.f;
        MV4(w0,  vh0, 0)  MV4(w1,  vh0, 4)  MV4(w2,  vh0, 8)  MV4(w3,  vh0, 12)
        MV4(w4,  vh0, 16) MV4(w5,  vh0, 20) MV4(w6,  vh0, 24) MV4(w7,  vh0, 28)
        MV4(w8,  vh0, 32) MV4(w9,  vh0, 36) MV4(w10, vh0, 40) MV4(w11, vh0, 44)
        MV4(w12, vh0, 48) MV4(w13, vh0, 52) MV4(w14, vh0, 56) MV4(w15, vh0, 60)
        MV4(w16, vh1, 0)  MV4(w17, vh1, 4)  MV4(w18, vh1, 8)  MV4(w19, vh1, 12)
        MV4(w20, vh1, 16) MV4(w21, vh1, 20) MV4(w22, vh1, 24) MV4(w23, vh1, 28)
        MV4(w24, vh1, 32) MV4(w25, vh1, 36) MV4(w26, vh1, 40) MV4(w27, vh1, 44)
        MV4(w28, vh1, 48) MV4(w29, vh1, 52) MV4(w30, vh1, 56) MV4(w31, vh1, 60)
        gates_sh[pos * 4 + (t >> 7)] = (a0 + a1) + (a2 + a3);
        __syncthreads();
        if (t < DD) {
            float4 pv = *(const float4*)&pbuf[buf][(s & 7) * 512 + t * 4];
            float4 gv = *(const float4*)&gates_sh[t * 4];
            float gi = gv.x + pv.x;
            float gf = gv.y + pv.y;
            float gg = gv.z + pv.z;
            float go = gv.w + pv.w;
            float ii = sigm(gi), ff = sigm(gf), tg = tanh_fast(gg), oo = sigm(go);
            c = ff * c + ii * tg;
            float hn = oo * tanh_fast(c);
            h_sh[t] = hn;
            if (s < SS - 1) {
                hbuf[s & 7] = hn;
                if ((s & 7) == 7) {
#pragma unroll
                    for (int k2 = 0; k2 < 8; ++k2) H[(s - 6 + k2) * DD + t] = hbuf[k2];
                }
            }
        }
        __syncthreads();
    }
    if (t < DD) {
#pragma unroll
        for (int k2 = 0; k2 < 7; ++k2) H[(505 + k2) * DD + t] = hbuf[k2];
    }
}

// ------- phase C: thread=step online softmax, 32 NAMED f32x4 h registers -------
#define LH(Q) f32x4 h##Q = hr4[Q];
#define DOT(Q, ACC) { f32x4 ev = ((const f32x4*)er)[Q]; \
    ACC = fmaf(ev.x, h##Q.x, ACC); ACC = fmaf(ev.y, h##Q.y, ACC); \
    ACC = fmaf(ev.z, h##Q.z, ACC); ACC = fmaf(ev.w, h##Q.w, ACC); }

__global__ __launch_bounds__(512, 1) void k_logits(const float* __restrict__ emb,
                                                   const float* __restrict__ H,
                                                   const unsigned long long* __restrict__ selw,
                                                   const unsigned long long* __restrict__ goodw,
                                                   float* __restrict__ part) {
    int b = blockIdx.x;          // 0..624
    int s = threadIdx.x;         // step index
    const f32x4* hr4 = (const f32x4*)(H + s * DD);
    LH(0)  LH(1)  LH(2)  LH(3)  LH(4)  LH(5)  LH(6)  LH(7)
    LH(8)  LH(9)  LH(10) LH(11) LH(12) LH(13) LH(14) LH(15)
    LH(16) LH(17) LH(18) LH(19) LH(20) LH(21) LH(22) LH(23)
    LH(24) LH(25) LH(26) LH(27) LH(28) LH(29) LH(30) LH(31)
    unsigned long long sw = selw[s * NW + b];
    unsigned long long gw = goodw[s * NW + b];
    float m = NEGF, se = 0.f, sl = 0.f, slg = 0.f;
    int rowbase = b * 64;
    for (int r = 0; r < 64; ++r) {
        const float* er = emb + (rowbase + r) * DD;    // block-uniform -> s_load
        float a0 = 0.f, a1 = 0.f, a2 = 0.f, a3 = 0.f;
        DOT(0, a0)  DOT(1, a1)  DOT(2, a2)  DOT(3, a3)
        DOT(4, a0)  DOT(5, a1)  DOT(6, a2)  DOT(7, a3)
        DOT(8, a0)  DOT(9, a1)  DOT(10, a2) DOT(11, a3)
        DOT(12, a0) DOT(13, a1) DOT(14, a2) DOT(15, a3)
        DOT(16, a0) DOT(17, a1) DOT(18, a2) DOT(19, a3)
        DOT(20, a0) DOT(21, a1) DOT(22, a2) DOT(23, a3)
        DOT(24, a0) DOT(25, a1) DOT(26, a2) DOT(27, a3)
        DOT(28, a0) DOT(29, a1) DOT(30, a2) DOT(31, a3)
        float acc = (a0 + a1) + (a2 + a3);
        float selb  = (float)((sw >> r) & 1ull);
        float goodb = (float)((gw >> r) & 1ull);
        float lm = (selb > 0.f) ? acc : NEGF;
        float nm = fmaxf(m, lm);
        float a = __expf(m - nm);
        float bx = selb * __expf(lm - nm);
        se = se * a + bx;
        sl = sl * a + bx * acc;
        m = nm;
        slg += goodb * acc;
    }
    int o = b * SS + s;
    part[0 * PARTN + o] = m;
    part[1 * PARTN + o] = se;
    part[2 * PARTN + o] = sl;
    part[3 * PARTN + o] = slg;
    part[4 * PARTN + o] = (float)__popcll(sw);
    part[5 * PARTN + o] = (float)__popcll(gw);
}

// ---------------- per-step merge of 625 block partials -------------------------
__global__ __launch_bounds__(64) void k_reduce(const float* __restrict__ part,
                                               float* __restrict__ Aout,
                                               float* __restrict__ Bout,
                                               float* __restrict__ actout) {
    int s = blockIdx.x;
    int t = threadIdx.x;     // 64 threads, one wave
    float m = NEGF, se = 0.f, sl = 0.f, slg = 0.f, np = 0.f, ng = 0.f;
    for (int b = t; b < NW; b += 64) {
        int o = b * SS + s;
        float m2  = part[0 * PARTN + o];
        float se2 = part[1 * PARTN + o];
        float sl2 = part[2 * PARTN + o];
        slg += part[3 * PARTN + o];
        np  += part[4 * PARTN + o];
        ng  += part[5 * PARTN + o];
        float nm = fmaxf(m, m2);
        float a = __expf(m - nm), a2 = __expf(m2 - nm);
        se = se * a + se2 * a2;
        sl = sl * a + sl2 * a2;
        m = nm;
    }
    for (int off = 32; off > 0; off >>= 1) {
        float m2  = __shfl_xor(m, off);
        float se2 = __shfl_xor(se, off);
        float sl2 = __shfl_xor(sl, off);
        slg += __shfl_xor(slg, off);
        np  += __shfl_xor(np, off);
        ng  += __shfl_xor(ng, off);
        float nm = fmaxf(m, m2);
        float a = __expf(m - nm), a2 = __expf(m2 - nm);
        se = se * a + se2 * a2;
        sl = sl * a + sl2 * a2;
        m = nm;
    }
    if (t == 0) {
        float lse = m + logf(se);
        float nbad = np - ng;
        int active = (ng > 0.5f) && (nbad > 0.5f);
        float ce = (ng * lse - slg) / fmaxf(ng, 1.f);
        float A = (nbad / fmaxf(np, 1.f)) * ce;
        float minus_ent = sl / se - lse;
        float B = ECOEF * (minus_ent / logf(fmaxf(np, 2.0f)));
        Aout[s] = A; Bout[s] = B; actout[s] = active ? 1.f : 0.f;
    }
}

// ---------------- exact sequential discount prefix + final sum -----------------
__global__ __launch_bounds__(64) void k_final(const float* __restrict__ A,
                                              const float* __restrict__ B,
                                              const float* __restrict__ act,
                                              float* __restrict__ out) {
    int lane = threadIdx.x;
    float loss = 0.f;
    int base = 0;
    for (int ch = 0; ch < 8; ++ch) {
        int s = ch * 64 + lane;
        bool a = act[s] > 0.5f;
        unsigned long long bal = __ballot(a);
        unsigned long long ltmask = (lane == 0) ? 0ull : (~0ull >> (64 - lane));
        int pre = __popcll(bal & ltmask);
        if (a) {
            float f = powf(DISCOUNT, (float)(base + pre));
            loss += f * A[s] + B[s];
        }
        base += __popcll(bal);
    }
    for (int off = 32; off > 0; off >>= 1) loss += __shfl_xor(loss, off);
    if (lane == 0) out[0] = loss / fmaxf((float)base, 1.f);
}

extern "C" void kernel_launch(void* const* d_in, const int* in_sizes, int n_in,
                              void* d_out, int out_size, void* d_ws, size_t ws_size,
                              hipStream_t stream) {
    (void)in_sizes; (void)n_in; (void)out_size; (void)ws_size;
    const float* feat    = (const float*)d_in[0];
    const int*   sel     = (const int*)d_in[1];
    const int*   good    = (const int*)d_in[2];
    const int*   sel_idx = (const int*)d_in[3];
    const float* W1      = (const float*)d_in[4];
    const float* b1      = (const float*)d_in[5];
    const float* W2      = (const float*)d_in[6];
    const float* b2      = (const float*)d_in[7];
    const float* init_h  = (const float*)d_in[8];
    const float* init_c  = (const float*)d_in[9];
    const float* Wih     = (const float*)d_in[10];
    const float* Whh     = (const float*)d_in[11];
    const float* bih     = (const float*)d_in[12];
    const float* bhh     = (const float*)d_in[13];
    float* out = (float*)d_out;
    char* ws = (char*)d_ws;

    float* emb    = (float*)(ws + 0);                         // 20,480,000 B
    float* hidden = (float*)(ws + 20480000);                  // 20,480,000 B
    float* P2     = (float*)(ws + 41025536);                  // 1,048,576 B
    float* H      = (float*)(ws + 42074112);                  // 262,144 B
    unsigned long long* selw  = (unsigned long long*)(ws + 42336256);   // 2,560,000 B
    unsigned long long* goodw = (unsigned long long*)(ws + 44896256);   // 2,560,000 B
    float* part   = (float*)(ws + 47456256);                  // 7,680,000 B
    float* Aarr   = (float*)(ws + 55136256);                  // 2048 B
    float* Barr   = (float*)(ws + 55138304);                  // 2048 B
    float* actarr = (float*)(ws + 55140352);                  // 2048 B

    k_pack  <<<NW, 256, 0, stream>>>(sel, good, selw, goodw);
    k_hidden<<<N_CL / 2, 256, 0, stream>>>(feat, W1, b1, hidden);
    k_emb   <<<NW, 256, 0, stream>>>(hidden, W2, b2, emb);
    k_pgemm <<<64, 256, 0, stream>>>(emb, sel_idx, Wih, bih, bhh, P2);
    k_lstm  <<<1, 512, 0, stream>>>(Whh, P2, init_h, init_c, H);
    k_logits<<<NW, 512, 0, stream>>>(emb, H, selw, goodw, part);
    k_reduce<<<SS, 64, 0, stream>>>(part, Aarr, Barr, actarr);
    k_final <<<1, 64, 0, stream>>>(Aarr, Barr, actarr, out);
}